// Round 8
// baseline (2164.966 us; speedup 1.0000x reference)
//
#include <hip/hip_runtime.h>
#include <math.h>

namespace {

constexpr int B = 16, T = 24, N = 207, C = 64, HOR = 12;
constexpr int BT = B * T;          // 384
constexpr int BN = B * N;          // 3312
constexpr int P = B * T * N;       // 79488
constexpr int NC = N * C;          // 13248

// ws layout (floats)
constexpr size_t H_OFF = 0;                         // P*C = 5,087,232
constexpr size_t A_OFF = 5087232;                   // bufA: seq1
constexpr size_t Q_OFF = A_OFF + 5087232;           // q: 635,904
constexpr size_t K_OFF = Q_OFF + 635904;            // k: 635,904
constexpr size_t B_OFF = K_OFF + 635904;            // bufB: 20,348,928 (v / xp / packs)
constexpr size_t WS_FLOATS = B_OFF + 20348928;      // 31,795,200

// offsets within bufB
constexpr size_t EP_OFF = 17000000;                 // embed pack: 15,104 floats
constexpr size_t PK_OFF = 18000000;                 // weight packs: 147,456 floats

__device__ __forceinline__ float wsum(float v) {
#pragma unroll
  for (int off = 32; off; off >>= 1) v += __shfl_xor(v, off);
  return v;
}
__device__ __forceinline__ float wmax(float v) {
#pragma unroll
  for (int off = 32; off; off >>= 1) v = fmaxf(v, __shfl_xor(v, off));
  return v;
}
__device__ __forceinline__ float rdlane(float v, int l) {
  return __uint_as_float(__builtin_amdgcn_readlane(__float_as_uint(v), l));
}

// One-time embed precompute (see layout comment in k_embed).
__global__ __launch_bounds__(256) void k_embed_pack(
    const float* __restrict__ nodee, const float* __restrict__ hw,
    const float* __restrict__ hb, const float* __restrict__ dw,
    const float* __restrict__ db, const float* __restrict__ ww,
    const float* __restrict__ wb, const float* __restrict__ inw,
    const float* __restrict__ inb, float* __restrict__ ep) {
  int e = blockIdx.x * 256 + threadIdx.x;
  if (e < 13248) {
    int n = e >> 6, c = e & 63;
    const float* w = inw + c * 65 + 1;
    float a = 0.f;
#pragma unroll
    for (int i = 0; i < 16; i++) a += w[i] * nodee[n * 16 + i];
    ep[e] = a;
  } else if (e < 13568) {
    int m = e - 13248;
    int which = m >> 6, c = m & 63;
    const float* w = inw + c * 65;
    float r = 0.f;
    if (which == 0) {
      r = w[0];
    } else if (which == 1) {
#pragma unroll
      for (int i = 0; i < 16; i++) r += w[17 + i] * hw[i];
    } else if (which == 2) {
#pragma unroll
      for (int i = 0; i < 16; i++) r += w[33 + i] * dw[i];
    } else if (which == 3) {
#pragma unroll
      for (int i = 0; i < 16; i++) r += w[49 + i] * ww[i];
    } else {
      r = inb[c];
#pragma unroll
      for (int i = 0; i < 16; i++)
        r += w[17 + i] * hb[i] + w[33 + i] * db[i] + w[49 + i] * wb[i];
    }
    ep[e] = r;
  } else if (e < 15104) {
    int m = e - 13568;
    int t = m >> 6, c = m & 63;
    float dv = expf((float)(c & ~1) * (-9.210340371976184f / 64.0f));
    float ang = (float)t * dv;
    ep[e] = (c & 1) ? cosf(ang) : sinf(ang);
  }
}

// H[b,t,n,c]: 7-term FMA from the pack. One block = 4 positions.
__global__ __launch_bounds__(256) void k_embed(
    const float* __restrict__ x, const float* __restrict__ ep,
    float* __restrict__ H) {
  int pos = blockIdx.x * 4 + (threadIdx.x >> 6);
  int c = threadIdx.x & 63;
  int n = pos % N;
  int t = (pos / N) % T;
  const float* xv = x + (size_t)pos * 4;
  float flow = xv[0], hour = xv[1], wkend = xv[2], day = xv[3];
  float acc = ep[13504 + c] + ep[13248 + c] * flow + ep[13312 + c] * hour +
              ep[13376 + c] * day + ep[13440 + c] * wkend + ep[n * 64 + c] +
              ep[13568 + t * 64 + c];
  H[(size_t)pos * 64 + c] = acc;
}

// All-layer weight repack: per l: w1t[c][j]=w1[j][c]; w2q quad-pack; taq quad-pack x4.
__global__ __launch_bounds__(256) void k_pack_all(
    const float* __restrict__ w1, const float* __restrict__ w2,
    const float* __restrict__ tqw, const float* __restrict__ tkw,
    const float* __restrict__ tvw, const float* __restrict__ tow,
    float* __restrict__ pk) {
  int e = blockIdx.x * 256 + threadIdx.x;  // 0..147455
  int l = e / 49152;
  int m = e % 49152;
  float* w1t = pk + l * 49152;
  float* w2q = w1t + 16384;
  float* taq = w2q + 16384;
  if (m < 16384) {
    int c = m >> 8, j = m & 255;
    w1t[m] = w1[l * 16384 + j * 64 + c];
  } else if (m < 32768) {
    int mm = m - 16384;
    int jq = mm >> 8, c = (mm & 255) >> 2, kk = mm & 3;
    w2q[mm] = w2[l * 16384 + c * 256 + jq * 4 + kk];
  } else {
    int m2 = m - 32768;
    int ph = m2 >> 12;
    int mm = m2 & 4095;
    int cq = mm >> 8, o = (mm & 255) >> 2, j = mm & 3;
    const float* src =
        (ph == 0 ? tqw : ph == 1 ? tkw : ph == 2 ? tvw : tow) + l * 4096;
    taq[ph * 4096 + mm] = src[o * 64 + 4 * cq + j];
  }
}

// one block per g=(b,t). q,k: (B,8,T,N) flat; v: (B,64,T,N) flat.
__global__ __launch_bounds__(256) void k_spatial_qkv(
    const float* __restrict__ H, const float* __restrict__ qw,
    const float* __restrict__ qb, const float* __restrict__ kw,
    const float* __restrict__ kb, const float* __restrict__ vw,
    const float* __restrict__ vb, float* __restrict__ q, float* __restrict__ k,
    float* __restrict__ v, int l) {
  __shared__ float hs[N * 65];  // padded
  int g = blockIdx.x;
  int b = g / T, t = g % T;
  const float* Hbt = H + (size_t)g * NC;
  for (int e = threadIdx.x; e < NC; e += 256) {
    int n = e >> 6, c = e & 63;
    hs[n * 65 + c] = Hbt[e];
  }
  __syncthreads();
  qw += l * 8 * 64; qb += l * 8;
  kw += l * 8 * 64; kb += l * 8;
  vw += l * 64 * 64; vb += l * 64;
  for (int e = threadIdx.x; e < 16 * N; e += 256) {
    int o = e / N, n = e % N;
    int oo = o & 7;
    const float* W = (o < 8 ? qw : kw) + oo * 64;
    float acc = (o < 8 ? qb : kb)[oo];
#pragma unroll
    for (int c = 0; c < 64; c++) acc += W[c] * hs[n * 65 + c];
    size_t oidx = ((size_t)(b * 8 + oo) * T + t) * N + n;
    if (o < 8) q[oidx] = acc; else k[oidx] = acc;
  }
  for (int e = threadIdx.x; e < 64 * N; e += 256) {
    int o = e / N, n = e % N;
    const float* W = vw + o * 64;
    float acc = vb[o];
#pragma unroll
    for (int c = 0; c < 64; c++) acc += W[c] * hs[n * 65 + c];
    v[((size_t)(b * 64 + o) * T + t) * N + n] = acc;
  }
}

// Fused spatial attention + PV + residual. One block per g.
// Per wave-row: double softmax (probs in s[0..3] across lanes), write attn row
// to d_out, then PV via readlane broadcasts against lane-owned v row in LDS.
__global__ __launch_bounds__(256, 2) void k_spatial_attn_pv(
    const float* __restrict__ q, const float* __restrict__ k,
    const float* __restrict__ adj, const float* __restrict__ v,
    float* __restrict__ attn_out, float* __restrict__ H) {
  __shared__ float qs[8 * 208], ks[8 * 208];
  __shared__ float vs[64 * 212];  // stride 212: 16B-aligned rows, conflict-free b128
  int g = blockIdx.x;
  const float* qg = q + (size_t)g * 1656;
  const float* kg = k + (size_t)g * 1656;
  for (int e = threadIdx.x; e < 1656; e += 256) {
    int c2 = e / N, n = e % N;
    qs[c2 * 208 + n] = qg[e];
    ks[c2 * 208 + n] = kg[e];
  }
  const float* vg = v + (size_t)g * NC;  // flat (B*T,64,N) view — matches ref reshape
  for (int e = threadIdx.x; e < NC; e += 256) {
    int c = e / N, n = e % N;
    vs[c * 212 + n] = vg[e];
  }
  for (int e = threadIdx.x; e < 320; e += 256) {  // zero pad cols 207..211
    int c = e / 5;
    vs[c * 212 + 207 + (e % 5)] = 0.f;
  }
  __syncthreads();
  int wave = threadIdx.x >> 6, lane = threadIdx.x & 63;
  float* Hg = H + (size_t)g * NC;
  for (int row = wave; row < N; row += 4) {
    float s[4];
    float mx = -INFINITY;
#pragma unroll
    for (int j = 0; j < 4; j++) {
      int m = lane + 64 * j;
      float acc = -INFINITY;
      if (m < N) {
        acc = 0.f;
#pragma unroll
        for (int c2 = 0; c2 < 8; c2++)
          acc += qs[c2 * 208 + row] * ks[c2 * 208 + m];
        acc *= 0.125f;  // 1/sqrt(C)
      }
      s[j] = acc;
      mx = fmaxf(mx, acc);
    }
    mx = wmax(mx);
    float sum = 0.f;
#pragma unroll
    for (int j = 0; j < 4; j++) {
      int m = lane + 64 * j;
      float e = (m < N) ? expf(s[j] - mx) : 0.f;
      s[j] = e;
      sum += e;
    }
    sum = wsum(sum);
    float inv = 1.f / sum;
    // second softmax over masked probabilities
    float mx2 = -INFINITY;
    bool ok[4];
#pragma unroll
    for (int j = 0; j < 4; j++) {
      int m = lane + 64 * j;
      float p = s[j] * inv;
      bool valid = (m < N) && (adj[row * N + m] != 0.0f);
      ok[j] = valid;
      s[j] = p;
      if (valid) mx2 = fmaxf(mx2, p);
    }
    mx2 = wmax(mx2);
    float sum2 = 0.f;
#pragma unroll
    for (int j = 0; j < 4; j++) {
      float e = ok[j] ? expf(s[j] - mx2) : 0.f;
      s[j] = e;
      sum2 += e;
    }
    sum2 = wsum(sum2);
    float inv2 = 1.f / sum2;
    float* orow = attn_out + ((size_t)g * N + row) * N;
#pragma unroll
    for (int j = 0; j < 4; j++) {
      int m = lane + 64 * j;
      if (m < N) orow[m] = s[j] * inv2;
    }
    // PV: H[row][lane] += inv2 * sum_col s[col] * v2[lane][col]
    const float* vrow = vs + lane * 212;
    float pacc0 = 0.f, pacc1 = 0.f, pacc2 = 0.f, pacc3 = 0.f;
#pragma unroll
    for (int j = 0; j < 3; j++) {
      float sj = s[j];
#pragma unroll
      for (int qq = 0; qq < 16; qq++) {
        int n4 = j * 16 + qq;
        float4 vv = *(const float4*)(vrow + n4 * 4);
        pacc0 += rdlane(sj, 4 * qq) * vv.x;
        pacc1 += rdlane(sj, 4 * qq + 1) * vv.y;
        pacc2 += rdlane(sj, 4 * qq + 2) * vv.z;
        pacc3 += rdlane(sj, 4 * qq + 3) * vv.w;
      }
    }
    {
      float sj = s[3];
#pragma unroll
      for (int qq = 0; qq < 4; qq++) {  // cols 192..207 (col 207: s==0, v==0)
        int n4 = 48 + qq;
        float4 vv = *(const float4*)(vrow + n4 * 4);
        pacc0 += rdlane(sj, 4 * qq) * vv.x;
        pacc1 += rdlane(sj, 4 * qq + 1) * vv.y;
        pacc2 += rdlane(sj, 4 * qq + 2) * vv.z;
        pacc3 += rdlane(sj, 4 * qq + 3) * vv.w;
      }
    }
    Hg[(size_t)row * 64 + lane] += inv2 * ((pacc0 + pacc1) + (pacc2 + pacc3));
  }
}

// temporal MHA fused per (b,n), LN1 fused at load; residual into H.
// Weights pre-quad-packed in taq (global, L1/L2-hot): taq4[ph*1024+cq*64+o].
__global__ __launch_bounds__(256) void k_temporal(
    float* __restrict__ H, const float* __restrict__ taq,
    const float* __restrict__ qb, const float* __restrict__ kb,
    const float* __restrict__ vb, const float* __restrict__ ob,
    const float* __restrict__ lnw, const float* __restrict__ lnb, int l) {
  __shared__ float xs[24 * 68], qs[24 * 68], ks[24 * 68], vs[24 * 68];
  __shared__ float ss[96 * 25];
  int bn = blockIdx.x;
  int b = bn / N, n = bn % N;
  size_t base = ((size_t)b * T * N + n) * 64;
  int lane = threadIdx.x & 63, tg = threadIdx.x >> 6;
  // load + LN1 (h = LN1(h + sp)): xs holds hl
  float lw = lnw[l * 64 + lane], lb = lnb[l * 64 + lane];
  for (int t = tg; t < 24; t += 4) {
    float xv = H[base + (size_t)t * NC + lane];
    float mean = wsum(xv) * (1.f / 64.f);
    float d = xv - mean;
    float var = wsum(d * d) * (1.f / 64.f);
    xs[t * 68 + lane] = d / sqrtf(var + 1e-5f) * lw + lb;
  }
  __syncthreads();
  const float4* wq_all = (const float4*)taq;
  const float* Bm[3] = {qb + l * 64, kb + l * 64, vb + l * 64};
  float* Dm[3] = {qs, ks, vs};
#pragma unroll
  for (int ph = 0; ph < 3; ph++) {
    const float4* wq = wq_all + ph * 1024;
    float acc[6];
    float bv = Bm[ph][lane];
#pragma unroll
    for (int i = 0; i < 6; i++) acc[i] = bv;
#pragma unroll 4
    for (int cq = 0; cq < 16; cq++) {
      float4 w = wq[cq * 64 + lane];
#pragma unroll
      for (int i = 0; i < 6; i++) {
        float4 xv = *(const float4*)(&xs[(tg * 6 + i) * 68 + cq * 4]);
        acc[i] += xv.x * w.x + xv.y * w.y + xv.z * w.z + xv.w * w.w;
      }
    }
    float* dst = Dm[ph];
#pragma unroll
    for (int i = 0; i < 6; i++) dst[(tg * 6 + i) * 68 + lane] = acc[i];
  }
  __syncthreads();
  // scores: 4 heads x 24 x 24 (float4 fragments)
  for (int e = threadIdx.x; e < 2304; e += 256) {
    int u = e % 24, t = (e / 24) % 24, h = e / 576;
    float a = 0.f;
#pragma unroll
    for (int dq = 0; dq < 4; dq++) {
      float4 qv = *(const float4*)(&qs[t * 68 + h * 16 + dq * 4]);
      float4 kv = *(const float4*)(&ks[u * 68 + h * 16 + dq * 4]);
      a += qv.x * kv.x + qv.y * kv.y + qv.z * kv.z + qv.w * kv.w;
    }
    ss[(h * 24 + t) * 25 + u] = a * 0.25f;  // 1/sqrt(HD)
  }
  __syncthreads();
  if (threadIdx.x < 96) {
    float* row = ss + threadIdx.x * 25;
    float mx = -INFINITY;
#pragma unroll
    for (int u = 0; u < 24; u++) mx = fmaxf(mx, row[u]);
    float sum = 0.f;
#pragma unroll
    for (int u = 0; u < 24; u++) {
      float e2 = expf(row[u] - mx);
      row[u] = e2;
      sum += e2;
    }
    float inv = 1.f / sum;
#pragma unroll
    for (int u = 0; u < 24; u++) row[u] *= inv;
  }
  __syncthreads();
  // apply: att -> qs (qs dead after scores)
  {
    int h = lane >> 4;
    float acc2[6];
#pragma unroll
    for (int i = 0; i < 6; i++) acc2[i] = 0.f;
    for (int u = 0; u < 24; u++) {
      float vsv = vs[u * 68 + lane];
#pragma unroll
      for (int i = 0; i < 6; i++)
        acc2[i] += ss[(h * 24 + (tg * 6 + i)) * 25 + u] * vsv;
    }
#pragma unroll
    for (int i = 0; i < 6; i++) qs[(tg * 6 + i) * 68 + lane] = acc2[i];
  }
  __syncthreads();
  // output projection + residual
  {
    const float4* wo = wq_all + 3 * 1024;
    float acc[6];
    float bv = ob[l * 64 + lane];
#pragma unroll
    for (int i = 0; i < 6; i++) acc[i] = bv;
#pragma unroll 4
    for (int cq = 0; cq < 16; cq++) {
      float4 w = wo[cq * 64 + lane];
#pragma unroll
      for (int i = 0; i < 6; i++) {
        float4 xv = *(const float4*)(&qs[(tg * 6 + i) * 68 + cq * 4]);
        acc[i] += xv.x * w.x + xv.y * w.y + xv.z * w.z + xv.w * w.w;
      }
    }
#pragma unroll
    for (int i = 0; i < 6; i++)
      H[base + (size_t)(tg * 6 + i) * NC + lane] =
          xs[(tg * 6 + i) * 68 + lane] + acc[i];
  }
}

// Fused LN2 + FFN1(relu) + FFN2 + residual; hid lives in LDS.
__global__ __launch_bounds__(256) void k_ffn(
    float* __restrict__ H, const float* __restrict__ lnw,
    const float* __restrict__ lnb, const float* __restrict__ w1t,
    const float* __restrict__ b1, const float* __restrict__ w2q,
    const float* __restrict__ b2, int l) {
  __shared__ float xs[24 * 66];
  __shared__ float hids[24 * 260];  // row stride 260 (1040B, 16B-aligned)
  int bn = blockIdx.x;
  int b = bn / N, n = bn % N;
  size_t base = ((size_t)b * T * N + n) * 64;
  int lane = threadIdx.x & 63, tg = threadIdx.x >> 6;
  for (int t = tg; t < 24; t += 4) {
    float xv = H[base + (size_t)t * NC + lane];
    float mean = wsum(xv) * (1.f / 64.f);
    float d = xv - mean;
    float var = wsum(d * d) * (1.f / 64.f);
    xs[t * 66 + lane] = d / sqrtf(var + 1e-5f) * lnw[l * 64 + lane] + lnb[l * 64 + lane];
  }
  __syncthreads();
  int j0 = lane * 4;
  float4 b4 = *(const float4*)(b1 + l * 256 + j0);
  float a0[6], a1[6], a2[6], a3[6];
#pragma unroll
  for (int i = 0; i < 6; i++) { a0[i] = b4.x; a1[i] = b4.y; a2[i] = b4.z; a3[i] = b4.w; }
  for (int c = 0; c < 64; c++) {
    float4 w4 = *(const float4*)(w1t + c * 256 + j0);
#pragma unroll
    for (int i = 0; i < 6; i++) {
      float xv = xs[(tg * 6 + i) * 66 + c];
      a0[i] += xv * w4.x;
      a1[i] += xv * w4.y;
      a2[i] += xv * w4.z;
      a3[i] += xv * w4.w;
    }
  }
#pragma unroll
  for (int i = 0; i < 6; i++) {
    int t = tg * 6 + i;
    float4 r = make_float4(fmaxf(a0[i], 0.f), fmaxf(a1[i], 0.f),
                           fmaxf(a2[i], 0.f), fmaxf(a3[i], 0.f));
    *(float4*)(&hids[t * 260 + j0]) = r;
  }
  __syncthreads();
  const float4* w2q4 = (const float4*)w2q;
  float acc[6];
#pragma unroll
  for (int i = 0; i < 6; i++) acc[i] = 0.f;
  for (int jq = 0; jq < 64; jq++) {
    float4 w = w2q4[jq * 64 + lane];
#pragma unroll
    for (int i = 0; i < 6; i++) {
      float4 hv = *(const float4*)(&hids[(tg * 6 + i) * 260 + jq * 4]);
      acc[i] += hv.x * w.x + hv.y * w.y + hv.z * w.z + hv.w * w.w;
    }
  }
  float bias = b2[l * 64 + lane];
#pragma unroll
  for (int i = 0; i < 6; i++) {
    int t = tg * 6 + i;
    H[base + (size_t)t * NC + lane] = xs[t * 66 + lane] + bias + acc[i];
  }
}

// GRU input projection: xp[t,bn,g] = bih + X . wih. 16 pairs per block.
__global__ __launch_bounds__(256) void k_gru_xp(
    const float* __restrict__ X, const float* __restrict__ wih,
    const float* __restrict__ bih, float* __restrict__ xp, int l) {
  __shared__ float ws_[192 * 65];
  __shared__ float xv[16 * 64];
  int p0 = blockIdx.x * 16;
  for (int e = threadIdx.x; e < 192 * 64; e += 256) {
    int gI = e >> 6, c = e & 63;
    ws_[gI * 65 + c] = wih[l * 12288 + e];
  }
  for (int e = threadIdx.x; e < 16 * 64; e += 256) {
    int s = e >> 6, c = e & 63;
    int p = p0 + s;
    int t = p / BN, bn = p % BN;
    float val;
    if (l == 0) {
      int b = bn / N, n = bn % N;
      val = X[(((size_t)b * T + t) * N + n) * 64 + c];
    } else {
      val = X[(size_t)p * 64 + c];  // seq1[t,bn,c]
    }
    xv[e] = val;
  }
  __syncthreads();
  for (int e = threadIdx.x; e < 16 * 192; e += 256) {
    int s = e / 192, gI = e % 192;
    float acc = bih[l * 192 + gI];
#pragma unroll
    for (int c = 0; c < 64; c++) acc += xv[s * 64 + c] * ws_[gI * 65 + c];
    xp[((size_t)(p0 + s)) * 192 + gI] = acc;
  }
}

// GRU recurrence: 8 samples/block; waves 0-2 hold gate weights in registers.
__global__ __launch_bounds__(256) void k_gru_scan(
    const float* __restrict__ xp, const float* __restrict__ whh,
    const float* __restrict__ bhh, float* __restrict__ seq_out, int l) {
  constexpr int S = 8;
  __shared__ float hprev[S][64];
  __shared__ float hg[3][S][64];
  __shared__ float xpbuf[2][S * 192];
  int bn0 = blockIdx.x * S;
  int lane = threadIdx.x & 63;
  int wv = threadIdx.x >> 6;

  float4 w4[16];
  if (wv < 3) {
    const float* wr = whh + l * 12288 + (wv * 64 + lane) * 64;
#pragma unroll
    for (int j = 0; j < 16; j++) w4[j] = *(const float4*)(wr + j * 4);
  }
  float b_r = bhh[l * 192 + lane];
  float b_z = bhh[l * 192 + 64 + lane];
  float b_n = bhh[l * 192 + 128 + lane];

  for (int e = threadIdx.x; e < S * 64; e += 256) ((float*)hprev)[e] = 0.f;
  {
    const float* src = xp + (size_t)bn0 * 192;
    for (int e = threadIdx.x; e < S * 192; e += 256) xpbuf[0][e] = src[e];
  }
  __syncthreads();

  for (int t = 0; t < T; t++) {
    int cur = t & 1;
    if (wv < 3) {
      float acc[S];
#pragma unroll
      for (int s = 0; s < S; s++) acc[s] = 0.f;
#pragma unroll
      for (int j = 0; j < 16; j++) {
        float4 w = w4[j];
#pragma unroll
        for (int s = 0; s < S; s++) {
          float4 hb = *(const float4*)(&hprev[s][j * 4]);
          acc[s] += w.x * hb.x + w.y * hb.y + w.z * hb.z + w.w * hb.w;
        }
      }
#pragma unroll
      for (int s = 0; s < S; s++) hg[wv][s][lane] = acc[s];
    } else {
      if (t + 1 < T) {
        const float* src = xp + ((size_t)(t + 1) * BN + bn0) * 192;
        float* dst = xpbuf[(t + 1) & 1];
        for (int e = lane * 4; e < S * 192; e += 256) {
          *(float4*)(dst + e) = *(const float4*)(src + e);
        }
      }
    }
    __syncthreads();
#pragma unroll
    for (int ii = 0; ii < 2; ii++) {
      int s = wv + 4 * ii;
      const float* xr = &xpbuf[cur][s * 192];
      float r = 1.f / (1.f + expf(-(xr[lane] + hg[0][s][lane] + b_r)));
      float z = 1.f / (1.f + expf(-(xr[64 + lane] + hg[1][s][lane] + b_z)));
      float nn = tanhf(xr[128 + lane] + r * (hg[2][s][lane] + b_n));
      float hp = hprev[s][lane];
      float hnew = (1.f - z) * nn + z * hp;
      hprev[s][lane] = hnew;
      seq_out[((size_t)t * BN + bn0 + s) * 64 + lane] = hnew;
    }
    __syncthreads();
  }
}

// prediction head: one block per bn.
__global__ __launch_bounds__(256) void k_pred(
    const float* __restrict__ seq2, const float* __restrict__ pw,
    const float* __restrict__ pb, float* __restrict__ out) {
  __shared__ float s_[1536];
  int bn = blockIdx.x;
  int b = bn / N, n = bn % N;
  for (int e = threadIdx.x; e < 1536; e += 256) {
    int t = e >> 6, c = e & 63;
    s_[c * 24 + t] = seq2[((size_t)t * BN + bn) * 64 + c];
  }
  __syncthreads();
  int wave = threadIdx.x >> 6, lane = threadIdx.x & 63;
  for (int hor = wave; hor < 12; hor += 4) {
    const float* w = pw + hor * 1536;
    float acc = 0.f;
#pragma unroll 4
    for (int kk = lane; kk < 1536; kk += 64) acc += s_[kk] * w[kk];
    acc = wsum(acc);
    if (lane == 0) out[(size_t)b * (HOR * N) + hor * N + n] = acc + pb[hor];
  }
}

}  // namespace

extern "C" void kernel_launch(void* const* d_in, const int* in_sizes, int n_in,
                              void* d_out, int out_size, void* d_ws, size_t ws_size,
                              hipStream_t stream) {
  const float* x       = (const float*)d_in[0];
  const float* adj     = (const float*)d_in[1];
  const float* nodee   = (const float*)d_in[2];
  const float* hour_w  = (const float*)d_in[3];
  const float* hour_b  = (const float*)d_in[4];
  const float* day_w   = (const float*)d_in[5];
  const float* day_b   = (const float*)d_in[6];
  const float* wk_w    = (const float*)d_in[7];
  const float* wk_b    = (const float*)d_in[8];
  const float* in_w    = (const float*)d_in[9];
  const float* in_b    = (const float*)d_in[10];
  const float* sa_qw   = (const float*)d_in[11];
  const float* sa_qb   = (const float*)d_in[12];
  const float* sa_kw   = (const float*)d_in[13];
  const float* sa_kb   = (const float*)d_in[14];
  const float* sa_vw   = (const float*)d_in[15];
  const float* sa_vb   = (const float*)d_in[16];
  const float* ta_qw   = (const float*)d_in[17];
  const float* ta_qb   = (const float*)d_in[18];
  const float* ta_kw   = (const float*)d_in[19];
  const float* ta_kb   = (const float*)d_in[20];
  const float* ta_vw   = (const float*)d_in[21];
  const float* ta_vb   = (const float*)d_in[22];
  const float* ta_ow   = (const float*)d_in[23];
  const float* ta_ob   = (const float*)d_in[24];
  const float* ln1_w   = (const float*)d_in[25];
  const float* ln1_b   = (const float*)d_in[26];
  const float* ln2_w   = (const float*)d_in[27];
  const float* ln2_b   = (const float*)d_in[28];
  const float* ffn_w1  = (const float*)d_in[29];
  const float* ffn_b1  = (const float*)d_in[30];
  const float* ffn_w2  = (const float*)d_in[31];
  const float* ffn_b2  = (const float*)d_in[32];
  const float* gru_wih = (const float*)d_in[33];
  const float* gru_whh = (const float*)d_in[34];
  const float* gru_bih = (const float*)d_in[35];
  const float* gru_bhh = (const float*)d_in[36];
  const float* pred_w  = (const float*)d_in[37];
  const float* pred_b  = (const float*)d_in[38];

  if (ws_size < WS_FLOATS * sizeof(float)) return;  // loud failure: output stays poisoned

  float* ws   = (float*)d_ws;
  float* H    = ws + H_OFF;
  float* bufA = ws + A_OFF;   // seq1 during GRU
  float* q    = ws + Q_OFF;
  float* k    = ws + K_OFF;
  float* bufB = ws + B_OFF;   // v | xp | ep | packs

  float* out       = (float*)d_out;
  float* attn_base = out + (size_t)B * HOR * N;  // 39744 (16B aligned)

  float* v   = bufB;
  float* xp  = bufB;
  float* ep  = bufB + EP_OFF;
  float* pk  = bufB + PK_OFF;

  k_embed_pack<<<60, 256, 0, stream>>>(nodee, hour_w, hour_b, day_w, day_b,
                                       wk_w, wk_b, in_w, in_b, ep);
  k_embed<<<P / 4, 256, 0, stream>>>(x, ep, H);
  k_pack_all<<<576, 256, 0, stream>>>(ffn_w1, ffn_w2, ta_qw, ta_kw, ta_vw,
                                      ta_ow, pk);

  for (int l = 0; l < 3; l++) {
    float* attn_l = attn_base + (size_t)l * BT * N * N;
    float* w1t = pk + (size_t)l * 49152;
    float* w2q = w1t + 16384;
    float* taq = w2q + 16384;
    k_spatial_qkv<<<BT, 256, 0, stream>>>(H, sa_qw, sa_qb, sa_kw, sa_kb, sa_vw,
                                          sa_vb, q, k, v, l);
    k_spatial_attn_pv<<<BT, 256, 0, stream>>>(q, k, adj, v, attn_l, H);
    k_temporal<<<BN, 256, 0, stream>>>(H, taq, ta_qb, ta_kb, ta_vb, ta_ob,
                                       ln1_w, ln1_b, l);
    k_ffn<<<BN, 256, 0, stream>>>(H, ln2_w, ln2_b, w1t, ffn_b1, w2q, ffn_b2, l);
  }

  k_gru_xp<<<P / 16, 256, 0, stream>>>(H, gru_wih, gru_bih, xp, 0);
  k_gru_scan<<<BN / 8, 256, 0, stream>>>(xp, gru_whh, gru_bhh, bufA, 0);
  k_gru_xp<<<P / 16, 256, 0, stream>>>(bufA, gru_wih, gru_bih, xp, 1);
  k_gru_scan<<<BN / 8, 256, 0, stream>>>(xp, gru_whh, gru_bhh, H, 1);

  k_pred<<<BN, 256, 0, stream>>>(H, pred_w, pred_b, out);
}

// Round 10
// 1993.226 us; speedup vs baseline: 1.0862x; 1.0862x over previous
//
#include <hip/hip_runtime.h>
#include <math.h>

namespace {

constexpr int B = 16, T = 24, N = 207, C = 64, HOR = 12;
constexpr int BT = B * T;          // 384
constexpr int BN = B * N;          // 3312
constexpr int P = B * T * N;       // 79488
constexpr int NC = N * C;          // 13248

// ws layout (floats)
constexpr size_t H_OFF = 0;                         // P*C = 5,087,232
constexpr size_t A_OFF = 5087232;                   // bufA: seq1
constexpr size_t Q_OFF = A_OFF + 5087232;           // q: 635,904
constexpr size_t K_OFF = Q_OFF + 635904;            // k: 635,904
constexpr size_t B_OFF = K_OFF + 635904;            // bufB: 20,348,928 (v / xp / packs)
constexpr size_t WS_FLOATS = B_OFF + 20348928;      // 31,795,200

// offsets within bufB
constexpr size_t EP_OFF = 17000000;                 // embed pack: 15,104 floats
constexpr size_t PK_OFF = 18000000;                 // weight packs: 147,456 floats

__device__ __forceinline__ float wsum(float v) {
#pragma unroll
  for (int off = 32; off; off >>= 1) v += __shfl_xor(v, off);
  return v;
}
__device__ __forceinline__ float wmax(float v) {
#pragma unroll
  for (int off = 32; off; off >>= 1) v = fmaxf(v, __shfl_xor(v, off));
  return v;
}

// One-time embed precompute (see layout comment in k_embed).
__global__ __launch_bounds__(256) void k_embed_pack(
    const float* __restrict__ nodee, const float* __restrict__ hw,
    const float* __restrict__ hb, const float* __restrict__ dw,
    const float* __restrict__ db, const float* __restrict__ ww,
    const float* __restrict__ wb, const float* __restrict__ inw,
    const float* __restrict__ inb, float* __restrict__ ep) {
  int e = blockIdx.x * 256 + threadIdx.x;
  if (e < 13248) {
    int n = e >> 6, c = e & 63;
    const float* w = inw + c * 65 + 1;
    float a = 0.f;
#pragma unroll
    for (int i = 0; i < 16; i++) a += w[i] * nodee[n * 16 + i];
    ep[e] = a;
  } else if (e < 13568) {
    int m = e - 13248;
    int which = m >> 6, c = m & 63;
    const float* w = inw + c * 65;
    float r = 0.f;
    if (which == 0) {
      r = w[0];
    } else if (which == 1) {
#pragma unroll
      for (int i = 0; i < 16; i++) r += w[17 + i] * hw[i];
    } else if (which == 2) {
#pragma unroll
      for (int i = 0; i < 16; i++) r += w[33 + i] * dw[i];
    } else if (which == 3) {
#pragma unroll
      for (int i = 0; i < 16; i++) r += w[49 + i] * ww[i];
    } else {
      r = inb[c];
#pragma unroll
      for (int i = 0; i < 16; i++)
        r += w[17 + i] * hb[i] + w[33 + i] * db[i] + w[49 + i] * wb[i];
    }
    ep[e] = r;
  } else if (e < 15104) {
    int m = e - 13568;
    int t = m >> 6, c = m & 63;
    float dv = expf((float)(c & ~1) * (-9.210340371976184f / 64.0f));
    float ang = (float)t * dv;
    ep[e] = (c & 1) ? cosf(ang) : sinf(ang);
  }
}

// H[b,t,n,c]: 7-term FMA from the pack. One block = 4 positions.
__global__ __launch_bounds__(256) void k_embed(
    const float* __restrict__ x, const float* __restrict__ ep,
    float* __restrict__ H) {
  int pos = blockIdx.x * 4 + (threadIdx.x >> 6);
  int c = threadIdx.x & 63;
  int n = pos % N;
  int t = (pos / N) % T;
  const float* xv = x + (size_t)pos * 4;
  float flow = xv[0], hour = xv[1], wkend = xv[2], day = xv[3];
  float acc = ep[13504 + c] + ep[13248 + c] * flow + ep[13312 + c] * hour +
              ep[13376 + c] * day + ep[13440 + c] * wkend + ep[n * 64 + c] +
              ep[13568 + t * 64 + c];
  H[(size_t)pos * 64 + c] = acc;
}

// All-layer weight repack: per l: w1t[c][j]=w1[j][c]; w2q quad-pack; taq quad-pack x4.
__global__ __launch_bounds__(256) void k_pack_all(
    const float* __restrict__ w1, const float* __restrict__ w2,
    const float* __restrict__ tqw, const float* __restrict__ tkw,
    const float* __restrict__ tvw, const float* __restrict__ tow,
    float* __restrict__ pk) {
  int e = blockIdx.x * 256 + threadIdx.x;  // 0..147455
  int l = e / 49152;
  int m = e % 49152;
  float* w1t = pk + l * 49152;
  float* w2q = w1t + 16384;
  float* taq = w2q + 16384;
  if (m < 16384) {
    int c = m >> 8, j = m & 255;
    w1t[m] = w1[l * 16384 + j * 64 + c];
  } else if (m < 32768) {
    int mm = m - 16384;
    int jq = mm >> 8, c = (mm & 255) >> 2, kk = mm & 3;
    w2q[mm] = w2[l * 16384 + c * 256 + jq * 4 + kk];
  } else {
    int m2 = m - 32768;
    int ph = m2 >> 12;
    int mm = m2 & 4095;
    int cq = mm >> 8, o = (mm & 255) >> 2, j = mm & 3;
    const float* src =
        (ph == 0 ? tqw : ph == 1 ? tkw : ph == 2 ? tvw : tow) + l * 4096;
    taq[ph * 4096 + mm] = src[o * 64 + 4 * cq + j];
  }
}

// one block per g=(b,t). q,k: (B,8,T,N) flat; v: (B,64,T,N) flat.
__global__ __launch_bounds__(256) void k_spatial_qkv(
    const float* __restrict__ H, const float* __restrict__ qw,
    const float* __restrict__ qb, const float* __restrict__ kw,
    const float* __restrict__ kb, const float* __restrict__ vw,
    const float* __restrict__ vb, float* __restrict__ q, float* __restrict__ k,
    float* __restrict__ v, int l) {
  __shared__ float hs[N * 65];  // padded
  int g = blockIdx.x;
  int b = g / T, t = g % T;
  const float* Hbt = H + (size_t)g * NC;
  for (int e = threadIdx.x; e < NC; e += 256) {
    int n = e >> 6, c = e & 63;
    hs[n * 65 + c] = Hbt[e];
  }
  __syncthreads();
  qw += l * 8 * 64; qb += l * 8;
  kw += l * 8 * 64; kb += l * 8;
  vw += l * 64 * 64; vb += l * 64;
  for (int e = threadIdx.x; e < 16 * N; e += 256) {
    int o = e / N, n = e % N;
    int oo = o & 7;
    const float* W = (o < 8 ? qw : kw) + oo * 64;
    float acc = (o < 8 ? qb : kb)[oo];
#pragma unroll
    for (int c = 0; c < 64; c++) acc += W[c] * hs[n * 65 + c];
    size_t oidx = ((size_t)(b * 8 + oo) * T + t) * N + n;
    if (o < 8) q[oidx] = acc; else k[oidx] = acc;
  }
  for (int e = threadIdx.x; e < 64 * N; e += 256) {
    int o = e / N, n = e % N;
    const float* W = vw + o * 64;
    float acc = vb[o];
#pragma unroll
    for (int c = 0; c < 64; c++) acc += W[c] * hs[n * 65 + c];
    v[((size_t)(b * 64 + o) * T + t) * N + n] = acc;
  }
}

// Fused spatial attention + PV + residual. Grid (g, row-half).
// Per round, each wave computes 4 attn rows (double softmax), stores final
// probs in its private LDS pbuf, then PV: one v b128 per lane reused by 4 rows
// whose p arrives as uniform-address LDS broadcasts. No readlane, 4x v reuse.
__global__ __launch_bounds__(256, 2) void k_spatial_attn_pv(
    const float* __restrict__ q, const float* __restrict__ k,
    const float* __restrict__ adj, const float* __restrict__ v,
    float* __restrict__ attn_out, float* __restrict__ H) {
  __shared__ float qs[8 * 208], ks[8 * 208];
  __shared__ float vs[64 * 212];      // 16B-aligned rows
  __shared__ float pbuf[4][4][212];   // per-wave probability rows
  int g = blockIdx.x;
  int rbeg = blockIdx.y * 104;
  int rend = min(rbeg + 104, N);
  const float* qg = q + (size_t)g * 1656;
  const float* kg = k + (size_t)g * 1656;
  for (int e = threadIdx.x; e < 1656; e += 256) {
    int c2 = e / N, n = e % N;
    qs[c2 * 208 + n] = qg[e];
    ks[c2 * 208 + n] = kg[e];
  }
  const float* vg = v + (size_t)g * NC;  // flat (B*T,64,N) view — matches ref reshape
  for (int e = threadIdx.x; e < NC; e += 256) {
    int c = e / N, n = e % N;
    vs[c * 212 + n] = vg[e];
  }
  for (int e = threadIdx.x; e < 320; e += 256) {  // zero pad cols 207..211
    int c = e / 5;
    vs[c * 212 + 207 + (e % 5)] = 0.f;
  }
  __syncthreads();
  int wave = threadIdx.x >> 6, lane = threadIdx.x & 63;
  float* Hg = H + (size_t)g * NC;
  const float* vrow = vs + lane * 212;
  for (int round = 0; round < 7; round++) {
    int row0 = rbeg + round * 16 + wave * 4;
#pragma unroll
    for (int i = 0; i < 4; i++) {
      int row = row0 + i;
      if (row < rend) {  // wave-uniform guard
        float s[4];
        float mx = -INFINITY;
#pragma unroll
        for (int j = 0; j < 4; j++) {
          int m = lane + 64 * j;
          float acc = -INFINITY;
          if (m < N) {
            acc = 0.f;
#pragma unroll
            for (int c2 = 0; c2 < 8; c2++)
              acc += qs[c2 * 208 + row] * ks[c2 * 208 + m];
            acc *= 0.125f;  // 1/sqrt(C)
          }
          s[j] = acc;
          mx = fmaxf(mx, acc);
        }
        mx = wmax(mx);
        float sum = 0.f;
#pragma unroll
        for (int j = 0; j < 4; j++) {
          int m = lane + 64 * j;
          float e = (m < N) ? expf(s[j] - mx) : 0.f;
          s[j] = e;
          sum += e;
        }
        sum = wsum(sum);
        float inv = 1.f / sum;
        float mx2 = -INFINITY;
        bool ok[4];
#pragma unroll
        for (int j = 0; j < 4; j++) {
          int m = lane + 64 * j;
          float p = s[j] * inv;
          bool valid = (m < N) && (adj[row * N + m] != 0.0f);
          ok[j] = valid;
          s[j] = p;
          if (valid) mx2 = fmaxf(mx2, p);
        }
        mx2 = wmax(mx2);
        float sum2 = 0.f;
#pragma unroll
        for (int j = 0; j < 4; j++) {
          float e = ok[j] ? expf(s[j] - mx2) : 0.f;
          s[j] = e;
          sum2 += e;
        }
        sum2 = wsum(sum2);
        float inv2 = 1.f / sum2;
        float* orow = attn_out + ((size_t)g * N + row) * N;
#pragma unroll
        for (int j = 0; j < 4; j++) {
          int m = lane + 64 * j;
          float pfin = s[j] * inv2;  // 0 for m >= N
          if (m < N) orow[m] = pfin;
          if (m < 212) pbuf[wave][i][m] = pfin;
        }
      }
    }
    // PV for the 4 rows (stale pbuf rows are discarded by the guard below)
    float acc[4] = {0.f, 0.f, 0.f, 0.f};
    for (int n4 = 0; n4 < 52; n4++) {
      float4 vv = *(const float4*)(vrow + n4 * 4);
#pragma unroll
      for (int i = 0; i < 4; i++) {
        float4 pv = *(const float4*)(&pbuf[wave][i][n4 * 4]);
        acc[i] += pv.x * vv.x + pv.y * vv.y + pv.z * vv.z + pv.w * vv.w;
      }
    }
#pragma unroll
    for (int i = 0; i < 4; i++) {
      int row = row0 + i;
      if (row < rend) Hg[(size_t)row * 64 + lane] += acc[i];
    }
  }
}

// temporal MHA fused per (b,n), LN1 fused at load; residual into H.
// Weights pre-quad-packed in taq (global, L1/L2-hot): taq4[ph*1024+cq*64+o].
__global__ __launch_bounds__(256) void k_temporal(
    float* __restrict__ H, const float* __restrict__ taq,
    const float* __restrict__ qb, const float* __restrict__ kb,
    const float* __restrict__ vb, const float* __restrict__ ob,
    const float* __restrict__ lnw, const float* __restrict__ lnb, int l) {
  __shared__ float xs[24 * 68], qs[24 * 68], ks[24 * 68], vs[24 * 68];
  __shared__ float ss[96 * 25];
  int bn = blockIdx.x;
  int b = bn / N, n = bn % N;
  size_t base = ((size_t)b * T * N + n) * 64;
  int lane = threadIdx.x & 63, tg = threadIdx.x >> 6;
  // load + LN1 (h = LN1(h + sp)): xs holds hl
  float lw = lnw[l * 64 + lane], lb = lnb[l * 64 + lane];
  for (int t = tg; t < 24; t += 4) {
    float xv = H[base + (size_t)t * NC + lane];
    float mean = wsum(xv) * (1.f / 64.f);
    float d = xv - mean;
    float var = wsum(d * d) * (1.f / 64.f);
    xs[t * 68 + lane] = d / sqrtf(var + 1e-5f) * lw + lb;
  }
  __syncthreads();
  const float4* wq_all = (const float4*)taq;
  const float* Bm[3] = {qb + l * 64, kb + l * 64, vb + l * 64};
  float* Dm[3] = {qs, ks, vs};
#pragma unroll
  for (int ph = 0; ph < 3; ph++) {
    const float4* wq = wq_all + ph * 1024;
    float acc[6];
    float bv = Bm[ph][lane];
#pragma unroll
    for (int i = 0; i < 6; i++) acc[i] = bv;
#pragma unroll 4
    for (int cq = 0; cq < 16; cq++) {
      float4 w = wq[cq * 64 + lane];
#pragma unroll
      for (int i = 0; i < 6; i++) {
        float4 xv = *(const float4*)(&xs[(tg * 6 + i) * 68 + cq * 4]);
        acc[i] += xv.x * w.x + xv.y * w.y + xv.z * w.z + xv.w * w.w;
      }
    }
    float* dst = Dm[ph];
#pragma unroll
    for (int i = 0; i < 6; i++) dst[(tg * 6 + i) * 68 + lane] = acc[i];
  }
  __syncthreads();
  // scores: 4 heads x 24 x 24 (float4 fragments)
  for (int e = threadIdx.x; e < 2304; e += 256) {
    int u = e % 24, t = (e / 24) % 24, h = e / 576;
    float a = 0.f;
#pragma unroll
    for (int dq = 0; dq < 4; dq++) {
      float4 qv = *(const float4*)(&qs[t * 68 + h * 16 + dq * 4]);
      float4 kv = *(const float4*)(&ks[u * 68 + h * 16 + dq * 4]);
      a += qv.x * kv.x + qv.y * kv.y + qv.z * kv.z + qv.w * kv.w;
    }
    ss[(h * 24 + t) * 25 + u] = a * 0.25f;  // 1/sqrt(HD)
  }
  __syncthreads();
  if (threadIdx.x < 96) {
    float* row = ss + threadIdx.x * 25;
    float mx = -INFINITY;
#pragma unroll
    for (int u = 0; u < 24; u++) mx = fmaxf(mx, row[u]);
    float sum = 0.f;
#pragma unroll
    for (int u = 0; u < 24; u++) {
      float e2 = expf(row[u] - mx);
      row[u] = e2;
      sum += e2;
    }
    float inv = 1.f / sum;
#pragma unroll
    for (int u = 0; u < 24; u++) row[u] *= inv;
  }
  __syncthreads();
  // apply: att -> qs (qs dead after scores)
  {
    int h = lane >> 4;
    float acc2[6];
#pragma unroll
    for (int i = 0; i < 6; i++) acc2[i] = 0.f;
    for (int u = 0; u < 24; u++) {
      float vsv = vs[u * 68 + lane];
#pragma unroll
      for (int i = 0; i < 6; i++)
        acc2[i] += ss[(h * 24 + (tg * 6 + i)) * 25 + u] * vsv;
    }
#pragma unroll
    for (int i = 0; i < 6; i++) qs[(tg * 6 + i) * 68 + lane] = acc2[i];
  }
  __syncthreads();
  // output projection + residual
  {
    const float4* wo = wq_all + 3 * 1024;
    float acc[6];
    float bv = ob[l * 64 + lane];
#pragma unroll
    for (int i = 0; i < 6; i++) acc[i] = bv;
#pragma unroll 4
    for (int cq = 0; cq < 16; cq++) {
      float4 w = wo[cq * 64 + lane];
#pragma unroll
      for (int i = 0; i < 6; i++) {
        float4 xv = *(const float4*)(&qs[(tg * 6 + i) * 68 + cq * 4]);
        acc[i] += xv.x * w.x + xv.y * w.y + xv.z * w.z + xv.w * w.w;
      }
    }
#pragma unroll
    for (int i = 0; i < 6; i++)
      H[base + (size_t)(tg * 6 + i) * NC + lane] =
          xs[(tg * 6 + i) * 68 + lane] + acc[i];
  }
}

// Fused LN2 + FFN1(relu) + FFN2 + residual; hid lives in LDS.
__global__ __launch_bounds__(256) void k_ffn(
    float* __restrict__ H, const float* __restrict__ lnw,
    const float* __restrict__ lnb, const float* __restrict__ w1t,
    const float* __restrict__ b1, const float* __restrict__ w2q,
    const float* __restrict__ b2, int l) {
  __shared__ float xs[24 * 66];
  __shared__ float hids[24 * 260];  // row stride 260 (1040B, 16B-aligned)
  int bn = blockIdx.x;
  int b = bn / N, n = bn % N;
  size_t base = ((size_t)b * T * N + n) * 64;
  int lane = threadIdx.x & 63, tg = threadIdx.x >> 6;
  for (int t = tg; t < 24; t += 4) {
    float xv = H[base + (size_t)t * NC + lane];
    float mean = wsum(xv) * (1.f / 64.f);
    float d = xv - mean;
    float var = wsum(d * d) * (1.f / 64.f);
    xs[t * 66 + lane] = d / sqrtf(var + 1e-5f) * lnw[l * 64 + lane] + lnb[l * 64 + lane];
  }
  __syncthreads();
  int j0 = lane * 4;
  float4 b4 = *(const float4*)(b1 + l * 256 + j0);
  float a0[6], a1[6], a2[6], a3[6];
#pragma unroll
  for (int i = 0; i < 6; i++) { a0[i] = b4.x; a1[i] = b4.y; a2[i] = b4.z; a3[i] = b4.w; }
  for (int c = 0; c < 64; c++) {
    float4 w4 = *(const float4*)(w1t + c * 256 + j0);
#pragma unroll
    for (int i = 0; i < 6; i++) {
      float xv = xs[(tg * 6 + i) * 66 + c];
      a0[i] += xv * w4.x;
      a1[i] += xv * w4.y;
      a2[i] += xv * w4.z;
      a3[i] += xv * w4.w;
    }
  }
#pragma unroll
  for (int i = 0; i < 6; i++) {
    int t = tg * 6 + i;
    float4 r = make_float4(fmaxf(a0[i], 0.f), fmaxf(a1[i], 0.f),
                           fmaxf(a2[i], 0.f), fmaxf(a3[i], 0.f));
    *(float4*)(&hids[t * 260 + j0]) = r;
  }
  __syncthreads();
  const float4* w2q4 = (const float4*)w2q;
  float acc[6];
#pragma unroll
  for (int i = 0; i < 6; i++) acc[i] = 0.f;
  for (int jq = 0; jq < 64; jq++) {
    float4 w = w2q4[jq * 64 + lane];
#pragma unroll
    for (int i = 0; i < 6; i++) {
      float4 hv = *(const float4*)(&hids[(tg * 6 + i) * 260 + jq * 4]);
      acc[i] += hv.x * w.x + hv.y * w.y + hv.z * w.z + hv.w * w.w;
    }
  }
  float bias = b2[l * 64 + lane];
#pragma unroll
  for (int i = 0; i < 6; i++) {
    int t = tg * 6 + i;
    H[base + (size_t)t * NC + lane] = xs[t * 66 + lane] + bias + acc[i];
  }
}

// GRU input projection: xp[t,bn,g] = bih + X . wih. 16 pairs per block.
__global__ __launch_bounds__(256) void k_gru_xp(
    const float* __restrict__ X, const float* __restrict__ wih,
    const float* __restrict__ bih, float* __restrict__ xp, int l) {
  __shared__ float ws_[192 * 65];
  __shared__ float xv[16 * 64];
  int p0 = blockIdx.x * 16;
  for (int e = threadIdx.x; e < 192 * 64; e += 256) {
    int gI = e >> 6, c = e & 63;
    ws_[gI * 65 + c] = wih[l * 12288 + e];
  }
  for (int e = threadIdx.x; e < 16 * 64; e += 256) {
    int s = e >> 6, c = e & 63;
    int p = p0 + s;
    int t = p / BN, bn = p % BN;
    float val;
    if (l == 0) {
      int b = bn / N, n = bn % N;
      val = X[(((size_t)b * T + t) * N + n) * 64 + c];
    } else {
      val = X[(size_t)p * 64 + c];  // seq1[t,bn,c]
    }
    xv[e] = val;
  }
  __syncthreads();
  for (int e = threadIdx.x; e < 16 * 192; e += 256) {
    int s = e / 192, gI = e % 192;
    float acc = bih[l * 192 + gI];
#pragma unroll
    for (int c = 0; c < 64; c++) acc += xv[s * 64 + c] * ws_[gI * 65 + c];
    xp[((size_t)(p0 + s)) * 192 + gI] = acc;
  }
}

// GRU recurrence: 8 samples/block; waves 0-2 hold gate weights in registers.
__global__ __launch_bounds__(256) void k_gru_scan(
    const float* __restrict__ xp, const float* __restrict__ whh,
    const float* __restrict__ bhh, float* __restrict__ seq_out, int l) {
  constexpr int S = 8;
  __shared__ float hprev[S][64];
  __shared__ float hg[3][S][64];
  __shared__ float xpbuf[2][S * 192];
  int bn0 = blockIdx.x * S;
  int lane = threadIdx.x & 63;
  int wv = threadIdx.x >> 6;

  float4 w4[16];
  if (wv < 3) {
    const float* wr = whh + l * 12288 + (wv * 64 + lane) * 64;
#pragma unroll
    for (int j = 0; j < 16; j++) w4[j] = *(const float4*)(wr + j * 4);
  }
  float b_r = bhh[l * 192 + lane];
  float b_z = bhh[l * 192 + 64 + lane];
  float b_n = bhh[l * 192 + 128 + lane];

  for (int e = threadIdx.x; e < S * 64; e += 256) ((float*)hprev)[e] = 0.f;
  {
    const float* src = xp + (size_t)bn0 * 192;
    for (int e = threadIdx.x; e < S * 192; e += 256) xpbuf[0][e] = src[e];
  }
  __syncthreads();

  for (int t = 0; t < T; t++) {
    int cur = t & 1;
    if (wv < 3) {
      float acc[S];
#pragma unroll
      for (int s = 0; s < S; s++) acc[s] = 0.f;
#pragma unroll
      for (int j = 0; j < 16; j++) {
        float4 w = w4[j];
#pragma unroll
        for (int s = 0; s < S; s++) {
          float4 hb = *(const float4*)(&hprev[s][j * 4]);
          acc[s] += w.x * hb.x + w.y * hb.y + w.z * hb.z + w.w * hb.w;
        }
      }
#pragma unroll
      for (int s = 0; s < S; s++) hg[wv][s][lane] = acc[s];
    } else {
      if (t + 1 < T) {
        const float* src = xp + ((size_t)(t + 1) * BN + bn0) * 192;
        float* dst = xpbuf[(t + 1) & 1];
        for (int e = lane * 4; e < S * 192; e += 256) {
          *(float4*)(dst + e) = *(const float4*)(src + e);
        }
      }
    }
    __syncthreads();
#pragma unroll
    for (int ii = 0; ii < 2; ii++) {
      int s = wv + 4 * ii;
      const float* xr = &xpbuf[cur][s * 192];
      float r = 1.f / (1.f + expf(-(xr[lane] + hg[0][s][lane] + b_r)));
      float z = 1.f / (1.f + expf(-(xr[64 + lane] + hg[1][s][lane] + b_z)));
      float nn = tanhf(xr[128 + lane] + r * (hg[2][s][lane] + b_n));
      float hp = hprev[s][lane];
      float hnew = (1.f - z) * nn + z * hp;
      hprev[s][lane] = hnew;
      seq_out[((size_t)t * BN + bn0 + s) * 64 + lane] = hnew;
    }
    __syncthreads();
  }
}

// prediction head: one block per bn.
__global__ __launch_bounds__(256) void k_pred(
    const float* __restrict__ seq2, const float* __restrict__ pw,
    const float* __restrict__ pb, float* __restrict__ out) {
  __shared__ float s_[1536];
  int bn = blockIdx.x;
  int b = bn / N, n = bn % N;
  for (int e = threadIdx.x; e < 1536; e += 256) {
    int t = e >> 6, c = e & 63;
    s_[c * 24 + t] = seq2[((size_t)t * BN + bn) * 64 + c];
  }
  __syncthreads();
  int wave = threadIdx.x >> 6, lane = threadIdx.x & 63;
  for (int hor = wave; hor < 12; hor += 4) {
    const float* w = pw + hor * 1536;
    float acc = 0.f;
#pragma unroll 4
    for (int kk = lane; kk < 1536; kk += 64) acc += s_[kk] * w[kk];
    acc = wsum(acc);
    if (lane == 0) out[(size_t)b * (HOR * N) + hor * N + n] = acc + pb[hor];
  }
}

}  // namespace

extern "C" void kernel_launch(void* const* d_in, const int* in_sizes, int n_in,
                              void* d_out, int out_size, void* d_ws, size_t ws_size,
                              hipStream_t stream) {
  const float* x       = (const float*)d_in[0];
  const float* adj     = (const float*)d_in[1];
  const float* nodee   = (const float*)d_in[2];
  const float* hour_w  = (const float*)d_in[3];
  const float* hour_b  = (const float*)d_in[4];
  const float* day_w   = (const float*)d_in[5];
  const float* day_b   = (const float*)d_in[6];
  const float* wk_w    = (const float*)d_in[7];
  const float* wk_b    = (const float*)d_in[8];
  const float* in_w    = (const float*)d_in[9];
  const float* in_b    = (const float*)d_in[10];
  const float* sa_qw   = (const float*)d_in[11];
  const float* sa_qb   = (const float*)d_in[12];
  const float* sa_kw   = (const float*)d_in[13];
  const float* sa_kb   = (const float*)d_in[14];
  const float* sa_vw   = (const float*)d_in[15];
  const float* sa_vb   = (const float*)d_in[16];
  const float* ta_qw   = (const float*)d_in[17];
  const float* ta_qb   = (const float*)d_in[18];
  const float* ta_kw   = (const float*)d_in[19];
  const float* ta_kb   = (const float*)d_in[20];
  const float* ta_vw   = (const float*)d_in[21];
  const float* ta_vb   = (const float*)d_in[22];
  const float* ta_ow   = (const float*)d_in[23];
  const float* ta_ob   = (const float*)d_in[24];
  const float* ln1_w   = (const float*)d_in[25];
  const float* ln1_b   = (const float*)d_in[26];
  const float* ln2_w   = (const float*)d_in[27];
  const float* ln2_b   = (const float*)d_in[28];
  const float* ffn_w1  = (const float*)d_in[29];
  const float* ffn_b1  = (const float*)d_in[30];
  const float* ffn_w2  = (const float*)d_in[31];
  const float* ffn_b2  = (const float*)d_in[32];
  const float* gru_wih = (const float*)d_in[33];
  const float* gru_whh = (const float*)d_in[34];
  const float* gru_bih = (const float*)d_in[35];
  const float* gru_bhh = (const float*)d_in[36];
  const float* pred_w  = (const float*)d_in[37];
  const float* pred_b  = (const float*)d_in[38];

  if (ws_size < WS_FLOATS * sizeof(float)) return;  // loud failure: output stays poisoned

  float* ws   = (float*)d_ws;
  float* H    = ws + H_OFF;
  float* bufA = ws + A_OFF;   // seq1 during GRU
  float* q    = ws + Q_OFF;
  float* k    = ws + K_OFF;
  float* bufB = ws + B_OFF;   // v | xp | ep | packs

  float* out       = (float*)d_out;
  float* attn_base = out + (size_t)B * HOR * N;  // 39744 (16B aligned)

  float* v   = bufB;
  float* xp  = bufB;
  float* ep  = bufB + EP_OFF;
  float* pk  = bufB + PK_OFF;

  k_embed_pack<<<60, 256, 0, stream>>>(nodee, hour_w, hour_b, day_w, day_b,
                                       wk_w, wk_b, in_w, in_b, ep);
  k_embed<<<P / 4, 256, 0, stream>>>(x, ep, H);
  k_pack_all<<<576, 256, 0, stream>>>(ffn_w1, ffn_w2, ta_qw, ta_kw, ta_vw,
                                      ta_ow, pk);

  for (int l = 0; l < 3; l++) {
    float* attn_l = attn_base + (size_t)l * BT * N * N;
    float* w1t = pk + (size_t)l * 49152;
    float* w2q = w1t + 16384;
    float* taq = w2q + 16384;
    k_spatial_qkv<<<BT, 256, 0, stream>>>(H, sa_qw, sa_qb, sa_kw, sa_kb, sa_vw,
                                          sa_vb, q, k, v, l);
    k_spatial_attn_pv<<<dim3(BT, 2), 256, 0, stream>>>(q, k, adj, v, attn_l, H);
    k_temporal<<<BN, 256, 0, stream>>>(H, taq, ta_qb, ta_kb, ta_vb, ta_ob,
                                       ln1_w, ln1_b, l);
    k_ffn<<<BN, 256, 0, stream>>>(H, ln2_w, ln2_b, w1t, ffn_b1, w2q, ffn_b2, l);
  }

  k_gru_xp<<<P / 16, 256, 0, stream>>>(H, gru_wih, gru_bih, xp, 0);
  k_gru_scan<<<BN / 8, 256, 0, stream>>>(xp, gru_whh, gru_bhh, bufA, 0);
  k_gru_xp<<<P / 16, 256, 0, stream>>>(bufA, gru_wih, gru_bih, xp, 1);
  k_gru_scan<<<BN / 8, 256, 0, stream>>>(xp, gru_whh, gru_bhh, H, 1);

  k_pred<<<BN, 256, 0, stream>>>(H, pred_w, pred_b, out);
}